// Round 13
// baseline (260.665 us; speedup 1.0000x reference)
//
#include <hip/hip_runtime.h>
#include <cstddef>

constexpr int Bb  = 4;
constexpr int Nn  = 2048;
constexpr int Cc  = 256;
constexpr int Hh  = 128;
constexpr int NHh = 8;
constexpr int DHh = 16;
constexpr int MTOK = Bb * Nn;           // 8192 tokens
#define LOG2E 1.4426950408889634f

typedef __attribute__((ext_vector_type(8))) short bf16x8;
typedef __attribute__((ext_vector_type(4))) short bf16x4;
typedef __attribute__((ext_vector_type(4))) float f32x4;

__device__ __forceinline__ short f32_to_bf16_rne(float f) {
    union { float f; unsigned int u; } c; c.f = f;
    unsigned int r = c.u + 0x7fffu + ((c.u >> 16) & 1u);
    return (short)(r >> 16);
}
__device__ __forceinline__ float bf16_to_f32(short s) {
    union { float f; unsigned int u; } c; c.u = ((unsigned int)(unsigned short)s) << 16;
    return c.f;
}
// RNE pack of two f32 -> packed bf16x2 (low = a, high = b).
__device__ __forceinline__ unsigned pack2_bf16(float a, float b) {
    unsigned r;
    asm("v_cvt_pk_bf16_f32 %0, %1, %2" : "=v"(r) : "v"(a), "v"(b));
    return r;
}

// ---------------------------------------------------------------------------
// fp32 -> bf16 conversion (weights + x) + zero the 4 quality accumulators
// ---------------------------------------------------------------------------
struct CvtJobs {
    const float* src[13];
    short*       dst[13];
    int          off[14];
    float*       qzero;
};

__global__ __launch_bounds__(256) void cvt_kernel(CvtJobs j) {
    const int gid = blockIdx.x * 256 + threadIdx.x;
    if (blockIdx.x == 0 && threadIdx.x < 4) j.qzero[threadIdx.x] = 0.f;
    if (gid >= j.off[13]) return;
    int k = 0;
    #pragma unroll
    for (int i = 0; i < 12; ++i) if (gid >= j.off[i + 1]) k = i + 1;
    const int idx = (gid - j.off[k]) * 4;
    float4 v = *(const float4*)(j.src[k] + idx);
    short o4[4] = { f32_to_bf16_rne(v.x), f32_to_bf16_rne(v.y),
                    f32_to_bf16_rne(v.z), f32_to_bf16_rne(v.w) };
    *(bf16x4*)(j.dst[k] + idx) = *(bf16x4*)o4;
}

// ---------------------------------------------------------------------------
// qkv projection GEMM, specialized K=128 (R7-verified, unchanged).
// ---------------------------------------------------------------------------
__global__ __launch_bounds__(256) void qkv_gemm_kernel(
    const short* __restrict__ X, const short* __restrict__ W,
    const float* __restrict__ bias, short* __restrict__ Yb)
{
    constexpr int K = 128, N = 384, ST = K + 8;
    __shared__ short As[64 * ST];
    __shared__ short Bs[64 * ST];

    const int tid  = threadIdx.x;
    const int lane = tid & 63;
    const int wv   = tid >> 6;
    const int col  = lane & 15;
    const int g    = lane >> 4;
    const int m0   = blockIdx.y * 64;
    const int n0   = blockIdx.x * 64;

    for (int i = tid; i < 64 * (K / 8); i += 256) {
        const int r = i / (K / 8), c = (i % (K / 8)) * 8;
        *(bf16x8*)&As[r * ST + c] = *(const bf16x8*)(X + (size_t)(m0 + r) * K + c);
        *(bf16x8*)&Bs[r * ST + c] = *(const bf16x8*)(W + (size_t)(n0 + r) * K + c);
    }
    __syncthreads();

    f32x4 acc[4] = {};
    #pragma unroll
    for (int k0 = 0; k0 < K; k0 += 32) {
        bf16x8 a = *(bf16x8*)&As[(wv * 16 + col) * ST + k0 + g * 8];
        #pragma unroll
        for (int jj = 0; jj < 4; ++jj) {
            bf16x8 b = *(bf16x8*)&Bs[(jj * 16 + col) * ST + k0 + g * 8];
            acc[jj] = __builtin_amdgcn_mfma_f32_16x16x32_bf16(a, b, acc[jj], 0, 0, 0);
        }
    }

    #pragma unroll
    for (int jj = 0; jj < 4; ++jj) {
        const int cn = n0 + jj * 16 + col;
        const float bb = bias[cn];
        #pragma unroll
        for (int r = 0; r < 4; ++r) {
            const int rm = m0 + wv * 16 + g * 4 + r;
            Yb[(size_t)rm * N + cn] = f32_to_bf16_rne(acc[jj][r] + bb);
        }
    }
}

// ---------------------------------------------------------------------------
// FUSED post-attention layer tail (R12-verified math), register-prefetch
// panel pipeline, two-barrier rounds (trailing __syncthreads is LOAD-BEARING
// per R11 post-mortem — do not remove).
// DO_HEAD=true (layer 1 only) additionally folds the entire head in:
//   LN2's bf16 output goes to LDS U1 (verified LN1->U1 handoff pattern)
//   instead of the hf/hb global write (no later consumers); 3 more panel
//   rounds (W1b x2, DW1b) ride the same pipeline; head scatter/epilogue is
//   the verified head_kernel re-parameterized to 16 rows (P2 aliases Ws).
// Removes the head dispatch + 10MB of spine traffic.
// ---------------------------------------------------------------------------
template<bool DO_HEAD>
__global__ __launch_bounds__(256) void postattn_kernel(
    const short* __restrict__ X,                                   // attno
    const short* __restrict__ Wo, const float* __restrict__ bo,
    const short* __restrict__ W1, const float* __restrict__ b1,
    const short* __restrict__ W2, const float* __restrict__ b2,
    float* __restrict__ hf, short* __restrict__ hb,
    const float* __restrict__ g1w, const float* __restrict__ b1w,
    const float* __restrict__ g2w, const float* __restrict__ b2w,
    const short* __restrict__ HW1b, const float* __restrict__ hb1,
    const short* __restrict__ HDW1b, const float* __restrict__ hdb1,
    const float* __restrict__ hw2, const float* __restrict__ hb2,
    const float* __restrict__ hdw2, const float* __restrict__ hdb2,
    float* __restrict__ out)
{
    __shared__ short As[16 * 136];
    __shared__ short Ws[64 * 136];
    __shared__ short U1[16 * 136];
    __shared__ short U2[16 * 264];
    float* P = (float*)Ws;                 // 16*130*4 = 8320B <= 17408B

    const int tid  = threadIdx.x;
    const int lane = tid & 63;
    const int wv   = tid >> 6;
    const int col  = lane & 15;
    const int g    = lane >> 4;
    const int m0   = blockIdx.x * 16;
    const int cb   = wv * 16;

    bf16x8 wreg[4];
    auto loadPanel = [&](const short* base, int stride) {
        #pragma unroll
        for (int j = 0; j < 4; ++j) {
            const int i = tid + j * 256;
            wreg[j] = *(const bf16x8*)(base + (size_t)(i / 16) * stride + (i % 16) * 8);
        }
    };
    auto writePanel = [&]() {
        #pragma unroll
        for (int j = 0; j < 4; ++j) {
            const int i = tid + j * 256;
            *(bf16x8*)&Ws[(i / 16) * 136 + (i % 16) * 8] = wreg[j];
        }
    };

    {   // stage As (one bf16x8 per thread)
        const int r = tid / 16, c = (tid % 16) * 8;
        *(bf16x8*)&As[r * 136 + c] = *(const bf16x8*)(X + (size_t)(m0 + r) * 128 + c);
    }
    loadPanel(Wo, 128);                    // prologue: panel 0

    // ---- attn out-proj (rounds 0,1) ----
    f32x4 ya[2] = {};
    #pragma unroll
    for (int ch = 0; ch < 2; ++ch) {
        writePanel();
        if (ch == 0) loadPanel(Wo + (size_t)64 * 128, 128);
        else         loadPanel(W1, 128);
        asm volatile("s_waitcnt lgkmcnt(0)" ::: "memory");
        __builtin_amdgcn_s_barrier();
        #pragma unroll
        for (int k0 = 0; k0 < 128; k0 += 32) {
            bf16x8 a = *(bf16x8*)&As[col * 136 + k0 + g * 8];
            bf16x8 b = *(bf16x8*)&Ws[(cb + col) * 136 + k0 + g * 8];
            ya[ch] = __builtin_amdgcn_mfma_f32_16x16x32_bf16(a, b, ya[ch], 0, 0, 0);
        }
        __syncthreads();
    }

    #pragma unroll
    for (int ch = 0; ch < 2; ++ch) {
        const int cn = ch * 64 + cb + col;
        const float bb = bo[cn];
        #pragma unroll
        for (int r = 0; r < 4; ++r)
            P[(g * 4 + r) * 130 + cn] = ya[ch][r] + bb;
    }
    __syncthreads();

    // ---- LN1: residual from global hf; fp32 result to regs, bf16 to U1 ----
    float2 resid[4];
    #pragma unroll
    for (int rr = 0; rr < 4; ++rr) {
        const int row = wv * 4 + rr;
        const size_t t = m0 + row;
        float2 pv = *(float2*)&P[row * 130 + 2 * lane];
        float2 hv = ((const float2*)(hf + t * Hh))[lane];
        float a0 = hv.x + pv.x, a1 = hv.y + pv.y;
        float sum = a0 + a1;
        #pragma unroll
        for (int off = 32; off > 0; off >>= 1) sum += __shfl_xor(sum, off);
        const float mean = sum * (1.f / 128.f);
        const float d0 = a0 - mean, d1 = a1 - mean;
        float vs = d0 * d0 + d1 * d1;
        #pragma unroll
        for (int off = 32; off > 0; off >>= 1) vs += __shfl_xor(vs, off);
        const float rstd = rsqrtf(vs * (1.f / 128.f) + 1e-5f);
        float2 gv = ((const float2*)g1w)[lane];
        float2 bv = ((const float2*)b1w)[lane];
        float2 r = { d0 * rstd * gv.x + bv.x, d1 * rstd * gv.y + bv.y };
        resid[rr] = r;
        *(unsigned*)&U1[row * 136 + 2 * lane] = pack2_bf16(r.x, r.y);
    }
    __syncthreads();       // P reads + U1 writes done before Ws restage / U1 reads

    // ---- FFN stage 1 (rounds 2..5): U2 = relu(U1 @ W1^T + b1) ----
    #pragma unroll
    for (int ch = 0; ch < 4; ++ch) {
        writePanel();
        if (ch < 3) loadPanel(W1 + (size_t)(ch + 1) * 64 * 128, 128);
        else        loadPanel(W2, 256);
        asm volatile("s_waitcnt lgkmcnt(0)" ::: "memory");
        __builtin_amdgcn_s_barrier();
        f32x4 y1 = {};
        #pragma unroll
        for (int k0 = 0; k0 < 128; k0 += 32) {
            bf16x8 a = *(bf16x8*)&U1[col * 136 + k0 + g * 8];
            bf16x8 b = *(bf16x8*)&Ws[(cb + col) * 136 + k0 + g * 8];
            y1 = __builtin_amdgcn_mfma_f32_16x16x32_bf16(a, b, y1, 0, 0, 0);
        }
        __syncthreads();
        const int cn = ch * 64 + cb + col;
        const float bb = b1[cn];
        #pragma unroll
        for (int r = 0; r < 4; ++r)
            U2[(g * 4 + r) * 264 + cn] = f32_to_bf16_rne(fmaxf(y1[r] + bb, 0.f));
        // U2 ds_writes covered by the next round's lgkmcnt(0)+barrier
    }

    // ---- FFN stage 2 (rounds 6..9): yb = U2 @ W2^T ----
    f32x4 yb[2] = {};
    #pragma unroll
    for (int ch2 = 0; ch2 < 2; ++ch2) {
        #pragma unroll
        for (int kh = 0; kh < 2; ++kh) {
            writePanel();
            const int pidx = ch2 * 2 + kh;
            if (pidx < 3) {
                const int nj = pidx + 1;
                loadPanel(W2 + (size_t)(nj >> 1) * 64 * 256 + (nj & 1) * 128, 256);
            } else if (DO_HEAD) {
                loadPanel(HW1b, 128);      // head panel 0 prefetched in round 9
            }
            asm volatile("s_waitcnt lgkmcnt(0)" ::: "memory");
            __builtin_amdgcn_s_barrier();
            #pragma unroll
            for (int k0 = 0; k0 < 128; k0 += 32) {
                bf16x8 a = *(bf16x8*)&U2[col * 264 + kh * 128 + k0 + g * 8];
                bf16x8 b = *(bf16x8*)&Ws[(cb + col) * 136 + k0 + g * 8];
                yb[ch2] = __builtin_amdgcn_mfma_f32_16x16x32_bf16(a, b, yb[ch2], 0, 0, 0);
            }
            __syncthreads();
        }
    }

    // ---- LN2 scatter + epilogue (residual from regs) ----
    #pragma unroll
    for (int ch2 = 0; ch2 < 2; ++ch2) {
        const int cn = ch2 * 64 + cb + col;
        const float bb = b2[cn];
        #pragma unroll
        for (int r = 0; r < 4; ++r)
            P[(g * 4 + r) * 130 + cn] = yb[ch2][r] + bb;
    }
    __syncthreads();

    #pragma unroll
    for (int rr = 0; rr < 4; ++rr) {
        const int row = wv * 4 + rr;
        const size_t t = m0 + row;
        float2 pv = *(float2*)&P[row * 130 + 2 * lane];
        float a0 = resid[rr].x + pv.x, a1 = resid[rr].y + pv.y;
        float sum = a0 + a1;
        #pragma unroll
        for (int off = 32; off > 0; off >>= 1) sum += __shfl_xor(sum, off);
        const float mean = sum * (1.f / 128.f);
        const float d0 = a0 - mean, d1 = a1 - mean;
        float vs = d0 * d0 + d1 * d1;
        #pragma unroll
        for (int off = 32; off > 0; off >>= 1) vs += __shfl_xor(vs, off);
        const float rstd = rsqrtf(vs * (1.f / 128.f) + 1e-5f);
        float2 gv = ((const float2*)g2w)[lane];
        float2 bv = ((const float2*)b2w)[lane];
        float2 r = { d0 * rstd * gv.x + bv.x, d1 * rstd * gv.y + bv.y };
        if (DO_HEAD) {
            // h consumed only by the head: bf16 to U1 (U1's last reader was
            // FFN stage 1, many barriers back). No hf/hb writes needed.
            *(unsigned*)&U1[row * 136 + 2 * lane] = pack2_bf16(r.x, r.y);
        } else {
            ((float2*)(hf + t * Hh))[lane] = r;
            *(unsigned*)&hb[t * Hh + lane * 2] = pack2_bf16(r.x, r.y);
        }
    }

    if (DO_HEAD) {
        __syncthreads();   // P reads + U1 writes done before Ws restage

        // ---- head GEMM (rounds 10..12): chunks W1b[0:64], W1b[64:128], DW1b ----
        f32x4 hy[3] = {};
        #pragma unroll
        for (int ch = 0; ch < 3; ++ch) {
            writePanel();
            if (ch == 0)      loadPanel(HW1b + (size_t)64 * 128, 128);
            else if (ch == 1) loadPanel(HDW1b, 128);
            asm volatile("s_waitcnt lgkmcnt(0)" ::: "memory");
            __builtin_amdgcn_s_barrier();
            #pragma unroll
            for (int k0 = 0; k0 < 128; k0 += 32) {
                bf16x8 a = *(bf16x8*)&U1[col * 136 + k0 + g * 8];
                bf16x8 b = *(bf16x8*)&Ws[(cb + col) * 136 + k0 + g * 8];
                hy[ch] = __builtin_amdgcn_mfma_f32_16x16x32_bf16(a, b, hy[ch], 0, 0, 0);
            }
            __syncthreads();
        }

        // ---- head scatter (P2 aliases Ws; 16 x 196 f32 = 12.5KB) ----
        float* P2 = (float*)Ws;
        #pragma unroll
        for (int ch = 0; ch < 3; ++ch) {
            const int cn = ch * 64 + cb + col;
            const float bb = (cn < 128) ? hb1[cn] : hdb1[cn - 128];
            #pragma unroll
            for (int r = 0; r < 4; ++r)
                P2[(g * 4 + r) * 196 + cn] = fmaxf(hy[ch][r] + bb, 0.f);
        }
        __syncthreads();

        // ---- head epilogue (verified head_kernel pattern, 4 rows/wave) ----
        const float w20 = hw2[2 * lane],       w21 = hw2[2 * lane + 1];
        const float w22 = hw2[128 + 2 * lane], w23 = hw2[129 + 2 * lane];
        const float w24 = hw2[256 + 2 * lane], w25 = hw2[257 + 2 * lane];
        const float dwl = hdw2[lane];
        float qacc = 0.f;
        #pragma unroll
        for (int rr = 0; rr < 4; ++rr) {
            const int row = wv * 4 + rr;
            const size_t t = m0 + row;
            const float x0 = P2[row * 196 + 2 * lane];
            const float x1 = P2[row * 196 + 2 * lane + 1];
            float s0 = x0 * w20 + x1 * w21;
            float s1 = x0 * w22 + x1 * w23;
            float s2 = x0 * w24 + x1 * w25;
            float d  = P2[row * 196 + 128 + lane] * dwl;
            #pragma unroll
            for (int off = 32; off > 0; off >>= 1) {
                s0 += __shfl_xor(s0, off);
                s1 += __shfl_xor(s1, off);
                s2 += __shfl_xor(s2, off);
                d  += __shfl_xor(d,  off);
            }
            if (lane == 0) {
                out[t * 3 + 0] = s0 + hb2[0];
                out[t * 3 + 1] = s1 + hb2[1];
                out[t * 3 + 2] = s2 + hb2[2];
                const float prob = 1.f / (1.f + __expf(-(d + hdb2[0])));
                out[24576 + t] = prob;
                qacc += prob;
            }
        }
        if (lane == 0)
            atomicAdd(&out[32768 + (m0 >> 11)], qacc * (1.f / (float)Nn));
    }
}

// ---------------------------------------------------------------------------
// Two-stage fused MLP — 16-row blocks (R12-verified), register-prefetch
// panel pipeline. Feature-fusion front-end (K=256, MID=128, DO_LN=0).
// ---------------------------------------------------------------------------
template<int K, int MID, bool DO_LN>
__global__ __launch_bounds__(256) void mlp2_kernel(
    const short* __restrict__ X,
    const short* __restrict__ W1, const float* __restrict__ b1,
    const short* __restrict__ W2, const float* __restrict__ b2,
    float* __restrict__ hf, short* __restrict__ hb,
    const float* __restrict__ gw, const float* __restrict__ bw)
{
    constexpr int STA = K + 8;
    constexpr int STU = MID + 8;
    constexpr int KP1  = K / 128;
    constexpr int KP2  = MID / 128;
    constexpr int NCH1 = MID / 64;
    constexpr int NP1  = NCH1 * KP1;
    constexpr int NP   = NP1 + 2 * KP2;
    __shared__ short As[16 * STA];
    __shared__ short Ws[64 * 136];
    __shared__ short U[16 * STU];
    float* P = (float*)Ws;                 // 8320B <= 17408B

    const int tid  = threadIdx.x;
    const int lane = tid & 63;
    const int wv   = tid >> 6;
    const int col  = lane & 15;
    const int g    = lane >> 4;
    const int m0   = blockIdx.x * 16;
    const int cb   = wv * 16;

    bf16x8 wreg[4];
    auto loadPanelIdx = [&](int idx) {
        const short* base;
        int stride;
        if (idx < NP1) {
            const int ch = idx / KP1, kh = idx % KP1;
            base = W1 + (size_t)(ch * 64) * K + kh * 128; stride = K;
        } else {
            const int jj = idx - NP1;
            const int ch2 = jj / KP2, kh = jj % KP2;
            base = W2 + (size_t)(ch2 * 64) * MID + kh * 128; stride = MID;
        }
        #pragma unroll
        for (int j = 0; j < 4; ++j) {
            const int i = tid + j * 256;
            wreg[j] = *(const bf16x8*)(base + (size_t)(i / 16) * stride + (i % 16) * 8);
        }
    };
    auto writePanel = [&]() {
        #pragma unroll
        for (int j = 0; j < 4; ++j) {
            const int i = tid + j * 256;
            *(bf16x8*)&Ws[(i / 16) * 136 + (i % 16) * 8] = wreg[j];
        }
    };

    for (int i = tid; i < 16 * (K / 8); i += 256) {
        const int r = i / (K / 8), c = (i % (K / 8)) * 8;
        *(bf16x8*)&As[r * STA + c] = *(const bf16x8*)(X + (size_t)(m0 + r) * K + c);
    }
    loadPanelIdx(0);
    int pidx = 0;

    // ---- stage 1: u = relu(X@W1^T + b1), u in LDS ----
    #pragma unroll
    for (int ch = 0; ch < NCH1; ++ch) {
        f32x4 ya = {};
        #pragma unroll
        for (int kh = 0; kh < KP1; ++kh) {
            writePanel();
            ++pidx;
            if (pidx < NP) loadPanelIdx(pidx);
            asm volatile("s_waitcnt lgkmcnt(0)" ::: "memory");
            __builtin_amdgcn_s_barrier();
            #pragma unroll
            for (int k0 = 0; k0 < 128; k0 += 32) {
                bf16x8 a = *(bf16x8*)&As[col * STA + kh * 128 + k0 + g * 8];
                bf16x8 b = *(bf16x8*)&Ws[(cb + col) * 136 + k0 + g * 8];
                ya = __builtin_amdgcn_mfma_f32_16x16x32_bf16(a, b, ya, 0, 0, 0);
            }
            __syncthreads();
        }
        const int cn = ch * 64 + cb + col;
        const float bb = b1[cn];
        #pragma unroll
        for (int r = 0; r < 4; ++r)
            U[(g * 4 + r) * STU + cn] = f32_to_bf16_rne(fmaxf(ya[r] + bb, 0.f));
    }

    // ---- stage 2: y = u@W2^T + b2 ----
    f32x4 yb[2] = {};
    #pragma unroll
    for (int ch2 = 0; ch2 < 2; ++ch2) {
        #pragma unroll
        for (int kh = 0; kh < KP2; ++kh) {
            writePanel();
            ++pidx;
            if (pidx < NP) loadPanelIdx(pidx);
            asm volatile("s_waitcnt lgkmcnt(0)" ::: "memory");
            __builtin_amdgcn_s_barrier();
            #pragma unroll
            for (int k0 = 0; k0 < 128; k0 += 32) {
                bf16x8 a = *(bf16x8*)&U[col * STU + kh * 128 + k0 + g * 8];
                bf16x8 b = *(bf16x8*)&Ws[(cb + col) * 136 + k0 + g * 8];
                yb[ch2] = __builtin_amdgcn_mfma_f32_16x16x32_bf16(a, b, yb[ch2], 0, 0, 0);
            }
            __syncthreads();
        }
    }

    // ---- P scatter (aliases Ws) + epilogue ----
    #pragma unroll
    for (int ch2 = 0; ch2 < 2; ++ch2) {
        const int cn = ch2 * 64 + cb + col;
        const float bb = b2[cn];
        #pragma unroll
        for (int r = 0; r < 4; ++r)
            P[(g * 4 + r) * 130 + cn] = yb[ch2][r] + bb;
    }
    __syncthreads();

    #pragma unroll
    for (int rr = 0; rr < 4; ++rr) {
        const int row = wv * 4 + rr;
        const size_t t = m0 + row;
        float2 pv = *(float2*)&P[row * 130 + 2 * lane];
        if (DO_LN) {
            float2 hv = ((const float2*)(hf + t * Hh))[lane];
            float a0 = hv.x + pv.x, a1 = hv.y + pv.y;
            float sum = a0 + a1;
            #pragma unroll
            for (int off = 32; off > 0; off >>= 1) sum += __shfl_xor(sum, off);
            const float mean = sum * (1.f / 128.f);
            const float d0 = a0 - mean, d1 = a1 - mean;
            float vs = d0 * d0 + d1 * d1;
            #pragma unroll
            for (int off = 32; off > 0; off >>= 1) vs += __shfl_xor(vs, off);
            const float rstd = rsqrtf(vs * (1.f / 128.f) + 1e-5f);
            float2 gv = ((const float2*)gw)[lane];
            float2 bv = ((const float2*)bw)[lane];
            float2 r = { d0 * rstd * gv.x + bv.x, d1 * rstd * gv.y + bv.y };
            ((float2*)(hf + t * Hh))[lane] = r;
            *(unsigned*)&hb[t * Hh + lane * 2] = pack2_bf16(r.x, r.y);
        } else {
            ((float2*)(hf + t * Hh))[lane] = pv;
            *(unsigned*)&hb[t * Hh + lane * 2] = pack2_bf16(pv.x, pv.y);
        }
    }
}

// ---------------------------------------------------------------------------
// MFMA flash attention — R12-green kernel, unchanged (no-max softmax,
// ones-MFMA row sum, reg-prefetch pipeline, raw lgkm-only barrier,
// setprio around the MFMA+exp2 cluster). The __syncthreads at tile top is
// LOAD-BEARING (phase separation, R11 post-mortem).
// ---------------------------------------------------------------------------
constexpr int KT = 128;
constexpr int KS = 28;
constexpr int VS = 132;

__global__ __launch_bounds__(256) void attn_kernel(
    const short* __restrict__ qkv, short* __restrict__ out)
{
    __shared__ short Ks[KT * KS];
    __shared__ short Vs[DHh * VS];

    const int tid  = threadIdx.x;
    const int lane = tid & 63;
    const int wv   = tid >> 6;
    const int col  = lane & 15;
    const int g    = lane >> 4;
    const int hd   = blockIdx.y;
    const int b    = blockIdx.z;
    const int q0   = blockIdx.x * 64 + wv * 16;

    const short* base = qkv + (size_t)b * Nn * 384;

    bf16x8 qf = {};
    if (g < 2) {
        bf16x8 qraw = *(const bf16x8*)(base + (size_t)(q0 + col) * 384 + hd * DHh + g * 8);
        const float qs = 0.25f * LOG2E;
        #pragma unroll
        for (int i = 0; i < 8; ++i)
            qf[i] = f32_to_bf16_rne(bf16_to_f32(qraw[i]) * qs);
    }

    f32x4 o    = {0.f, 0.f, 0.f, 0.f};
    f32x4 lacc = {0.f, 0.f, 0.f, 0.f};
    const short one_bf16 = (short)0x3F80;
    const bf16x8 ones = { one_bf16, one_bf16, one_bf16, one_bf16,
                          one_bf16, one_bf16, one_bf16, one_bf16 };

    const int ksr = tid >> 1;
    const int ksd = (tid & 1) * 8;
    const int va  = tid >> 2;
    const int vd  = (tid & 3) * 4;

    const short* kptr = base + (size_t)ksr * 384 + Hh + hd * DHh + ksd;
    const short* vptr = base + (size_t)(2 * va) * 384 + 2 * Hh + hd * DHh + vd;
    bf16x8 kreg = *(const bf16x8*)kptr;
    bf16x4 vr0  = *(const bf16x4*)vptr;
    bf16x4 vr1  = *(const bf16x4*)(vptr + 384);

    for (int kt = 0; kt < Nn; kt += KT) {
        __syncthreads();

        *(bf16x8*)&Ks[ksr * KS + ksd] = kreg;
        {
            unsigned a0 = ((const unsigned*)&vr0)[0], a1 = ((const unsigned*)&vr0)[1];
            unsigned b0 = ((const unsigned*)&vr1)[0], b1 = ((const unsigned*)&vr1)[1];
            *(unsigned*)&Vs[(vd + 0) * VS + 2 * va] = __builtin_amdgcn_perm(b0, a0, 0x05040100);
            *(unsigned*)&Vs[(vd + 1) * VS + 2 * va] = __builtin_amdgcn_perm(b0, a0, 0x07060302);
            *(unsigned*)&Vs[(vd + 2) * VS + 2 * va] = __builtin_amdgcn_perm(b1, a1, 0x05040100);
            *(unsigned*)&Vs[(vd + 3) * VS + 2 * va] = __builtin_amdgcn_perm(b1, a1, 0x07060302);
        }

        if (kt + KT < Nn) {
            kptr += KT * 384;
            vptr += KT * 384;
            kreg = *(const bf16x8*)kptr;
            vr0  = *(const bf16x4*)vptr;
            vr1  = *(const bf16x4*)(vptr + 384);
        }

        asm volatile("s_waitcnt lgkmcnt(0)" ::: "memory");
        __builtin_amdgcn_s_barrier();

        __builtin_amdgcn_s_setprio(1);
        #pragma unroll
        for (int s = 0; s < 4; ++s) {
            bf16x8 kf0 = {}, kf1 = {};
            if (g < 2) {
                kf0 = *(bf16x8*)&Ks[(s * 32 + col) * KS + g * 8];
                kf1 = *(bf16x8*)&Ks[(s * 32 + 16 + col) * KS + g * 8];
            }
            f32x4 z = {0.f, 0.f, 0.f, 0.f};
            f32x4 sA = __builtin_amdgcn_mfma_f32_16x16x32_bf16(kf0, qf, z, 0, 0, 0);
            f32x4 sB = __builtin_amdgcn_mfma_f32_16x16x32_bf16(kf1, qf, z, 0, 0, 0);

            union { bf16x8 v; unsigned u[4]; } pf;
            pf.u[0] = pack2_bf16(__builtin_amdgcn_exp2f(sA[0]),
                                 __builtin_amdgcn_exp2f(sA[1]));
            pf.u[1] = pack2_bf16(__builtin_amdgcn_exp2f(sA[2]),
                                 __builtin_amdgcn_exp2f(sA[3]));
            pf.u[2] = pack2_bf16(__builtin_amdgcn_exp2f(sB[0]),
                                 __builtin_amdgcn_exp2f(sB[1]));
            pf.u[3] = pack2_bf16(__builtin_amdgcn_exp2f(sB[2]),
                                 __builtin_amdgcn_exp2f(sB[3]));

            bf16x8 vf;
            ((bf16x4*)&vf)[0] = *(bf16x4*)&Vs[col * VS + s * 32 + g * 4];
            ((bf16x4*)&vf)[1] = *(bf16x4*)&Vs[col * VS + s * 32 + 16 + g * 4];

            o    = __builtin_amdgcn_mfma_f32_16x16x32_bf16(pf.v, vf,   o,    0, 0, 0);
            lacc = __builtin_amdgcn_mfma_f32_16x16x32_bf16(pf.v, ones, lacc, 0, 0, 0);
        }
        __builtin_amdgcn_s_setprio(0);
    }

    #pragma unroll
    for (int r = 0; r < 4; ++r) {
        const float inv = __builtin_amdgcn_rcpf(lacc[r]);
        out[(size_t)(b * Nn + q0 + g * 4 + r) * Hh + hd * DHh + col] =
            f32_to_bf16_rne(o[r] * inv);
    }
}

// ---------------------------------------------------------------------------
extern "C" void kernel_launch(void* const* d_in, const int* in_sizes, int n_in,
                              void* d_out, int out_size, void* d_ws, size_t ws_size,
                              hipStream_t stream)
{
    char* W8 = (char*)d_ws;
    float* hf   = (float*)(W8 + 0);            // 4MB  fp32 residual spine
    short* hb   = (short*)(W8 + 4194304);      // 2MB  bf16 mirror
    short* wb   = (short*)(W8 + 6291456);      // 1MB  bf16 weights
    char*  regA = W8 + 7340032;                // 6MB  xb / qkvb
    char*  regB = W8 + 13631488;               // 2MB  attno

    short* xb    = (short*)regA;               // [8192,256]
    short* qkvb  = (short*)regA;               // [8192,384]
    short* attno = (short*)regB;               // [8192,128]
    float* out   = (float*)d_out;

    const int wsz[12]  = {32768,16384,49152,16384,32768,32768,49152,16384,32768,32768,16384,8192};
    const int wsrc[12] = {1, 3, 5, 7, 9, 11, 17, 19, 21, 23, 29, 33};
    int woff[13]; woff[0] = 0;
    for (int i = 0; i < 12; ++i) woff[i + 1] = woff[i] + wsz[i];

    CvtJobs jobs;
    int acc = 0;
    for (int i = 0; i < 12; ++i) {
        jobs.src[i] = (const float*)d_in[wsrc[i]];
        jobs.dst[i] = wb + woff[i];
        jobs.off[i] = acc;
        acc += wsz[i] / 4;
    }
    jobs.src[12] = (const float*)d_in[0];
    jobs.dst[12] = xb;
    jobs.off[12] = acc;
    acc += (MTOK * Cc) / 4;
    jobs.off[13] = acc;
    jobs.qzero = out + 32768;

    hipLaunchKernelGGL(cvt_kernel, dim3((acc + 255) / 256), dim3(256), 0, stream, jobs);

    // feature fusion: h = relu(x@fw1^T+b1)@fw2^T+b2  (one fused dispatch)
    hipLaunchKernelGGL((mlp2_kernel<256, 128, false>), dim3(MTOK / 16), dim3(256), 0,
                       stream, xb, wb + woff[0], (const float*)d_in[2],
                       wb + woff[1], (const float*)d_in[4], hf, hb, nullptr, nullptr);

    for (int l = 0; l < 2; ++l) {
        const int ib = 5 + l * 12;
        const int wbase = 2 + l * 4;
        hipLaunchKernelGGL(qkv_gemm_kernel, dim3(384 / 64, MTOK / 64), dim3(256), 0, stream,
                           hb, wb + woff[wbase + 0], (const float*)d_in[ib + 1], qkvb);
        hipLaunchKernelGGL(attn_kernel, dim3(Nn / 64, NHh, Bb), dim3(256), 0, stream,
                           qkvb, attno);
        if (l == 0) {
            hipLaunchKernelGGL((postattn_kernel<false>), dim3(MTOK / 16), dim3(256), 0, stream,
                               attno, wb + woff[wbase + 1], (const float*)d_in[ib + 3],
                               wb + woff[wbase + 2], (const float*)d_in[ib + 5],
                               wb + woff[wbase + 3], (const float*)d_in[ib + 7],
                               hf, hb,
                               (const float*)d_in[ib + 8], (const float*)d_in[ib + 9],
                               (const float*)d_in[ib + 10], (const float*)d_in[ib + 11],
                               nullptr, nullptr, nullptr, nullptr,
                               nullptr, nullptr, nullptr, nullptr, nullptr);
        } else {
            // layer 1: fused out-proj + LN1 + FFN + LN2 + HEAD (one dispatch)
            hipLaunchKernelGGL((postattn_kernel<true>), dim3(MTOK / 16), dim3(256), 0, stream,
                               attno, wb + woff[wbase + 1], (const float*)d_in[ib + 3],
                               wb + woff[wbase + 2], (const float*)d_in[ib + 5],
                               wb + woff[wbase + 3], (const float*)d_in[ib + 7],
                               hf, hb,
                               (const float*)d_in[ib + 8], (const float*)d_in[ib + 9],
                               (const float*)d_in[ib + 10], (const float*)d_in[ib + 11],
                               wb + woff[10], (const float*)d_in[30],
                               wb + woff[11], (const float*)d_in[34],
                               (const float*)d_in[31], (const float*)d_in[32],
                               (const float*)d_in[35], (const float*)d_in[36], out);
        }
    }
}

// Round 14
// 251.913 us; speedup vs baseline: 1.0347x; 1.0347x over previous
//
#include <hip/hip_runtime.h>
#include <cstddef>

constexpr int Bb  = 4;
constexpr int Nn  = 2048;
constexpr int Cc  = 256;
constexpr int Hh  = 128;
constexpr int NHh = 8;
constexpr int DHh = 16;
constexpr int MTOK = Bb * Nn;           // 8192 tokens
#define LOG2E 1.4426950408889634f

typedef __attribute__((ext_vector_type(8))) short bf16x8;
typedef __attribute__((ext_vector_type(4))) short bf16x4;
typedef __attribute__((ext_vector_type(4))) float f32x4;

__device__ __forceinline__ short f32_to_bf16_rne(float f) {
    union { float f; unsigned int u; } c; c.f = f;
    unsigned int r = c.u + 0x7fffu + ((c.u >> 16) & 1u);
    return (short)(r >> 16);
}
__device__ __forceinline__ float bf16_to_f32(short s) {
    union { float f; unsigned int u; } c; c.u = ((unsigned int)(unsigned short)s) << 16;
    return c.f;
}
// RNE pack of two f32 -> packed bf16x2 (low = a, high = b).
__device__ __forceinline__ unsigned pack2_bf16(float a, float b) {
    unsigned r;
    asm("v_cvt_pk_bf16_f32 %0, %1, %2" : "=v"(r) : "v"(a), "v"(b));
    return r;
}

// ---------------------------------------------------------------------------
// fp32 -> bf16 conversion (weights + x) + zero the 4 quality accumulators
// ---------------------------------------------------------------------------
struct CvtJobs {
    const float* src[13];
    short*       dst[13];
    int          off[14];
    float*       qzero;
};

__global__ __launch_bounds__(256) void cvt_kernel(CvtJobs j) {
    const int gid = blockIdx.x * 256 + threadIdx.x;
    if (blockIdx.x == 0 && threadIdx.x < 4) j.qzero[threadIdx.x] = 0.f;
    if (gid >= j.off[13]) return;
    int k = 0;
    #pragma unroll
    for (int i = 0; i < 12; ++i) if (gid >= j.off[i + 1]) k = i + 1;
    const int idx = (gid - j.off[k]) * 4;
    float4 v = *(const float4*)(j.src[k] + idx);
    short o4[4] = { f32_to_bf16_rne(v.x), f32_to_bf16_rne(v.y),
                    f32_to_bf16_rne(v.z), f32_to_bf16_rne(v.w) };
    *(bf16x4*)(j.dst[k] + idx) = *(bf16x4*)o4;
}

// ---------------------------------------------------------------------------
// qkv projection GEMM, specialized K=128 (R7-verified, unchanged).
// ---------------------------------------------------------------------------
__global__ __launch_bounds__(256) void qkv_gemm_kernel(
    const short* __restrict__ X, const short* __restrict__ W,
    const float* __restrict__ bias, short* __restrict__ Yb)
{
    constexpr int K = 128, N = 384, ST = K + 8;
    __shared__ short As[64 * ST];
    __shared__ short Bs[64 * ST];

    const int tid  = threadIdx.x;
    const int lane = tid & 63;
    const int wv   = tid >> 6;
    const int col  = lane & 15;
    const int g    = lane >> 4;
    const int m0   = blockIdx.y * 64;
    const int n0   = blockIdx.x * 64;

    for (int i = tid; i < 64 * (K / 8); i += 256) {
        const int r = i / (K / 8), c = (i % (K / 8)) * 8;
        *(bf16x8*)&As[r * ST + c] = *(const bf16x8*)(X + (size_t)(m0 + r) * K + c);
        *(bf16x8*)&Bs[r * ST + c] = *(const bf16x8*)(W + (size_t)(n0 + r) * K + c);
    }
    __syncthreads();

    f32x4 acc[4] = {};
    #pragma unroll
    for (int k0 = 0; k0 < K; k0 += 32) {
        bf16x8 a = *(bf16x8*)&As[(wv * 16 + col) * ST + k0 + g * 8];
        #pragma unroll
        for (int jj = 0; jj < 4; ++jj) {
            bf16x8 b = *(bf16x8*)&Bs[(jj * 16 + col) * ST + k0 + g * 8];
            acc[jj] = __builtin_amdgcn_mfma_f32_16x16x32_bf16(a, b, acc[jj], 0, 0, 0);
        }
    }

    #pragma unroll
    for (int jj = 0; jj < 4; ++jj) {
        const int cn = n0 + jj * 16 + col;
        const float bb = bias[cn];
        #pragma unroll
        for (int r = 0; r < 4; ++r) {
            const int rm = m0 + wv * 16 + g * 4 + r;
            Yb[(size_t)rm * N + cn] = f32_to_bf16_rne(acc[jj][r] + bb);
        }
    }
}

// ---------------------------------------------------------------------------
// FUSED post-attention layer tail (R12-verified), register-prefetch panel
// pipeline, two-barrier rounds. NOTES from post-mortems:
//  - R11: trailing __syncthreads per round is LOAD-BEARING (phase separator;
//    removing it doubled LDS bank conflicts and drifted absmax).
//  - R13: folding the head in here REGRESSED +6.4us (2x head staging across
//    512 blocks + longer critical path outweigh one saved dispatch).
// ---------------------------------------------------------------------------
__global__ __launch_bounds__(256) void postattn_kernel(
    const short* __restrict__ X,                                   // attno
    const short* __restrict__ Wo, const float* __restrict__ bo,
    const short* __restrict__ W1, const float* __restrict__ b1,
    const short* __restrict__ W2, const float* __restrict__ b2,
    float* __restrict__ hf, short* __restrict__ hb,
    const float* __restrict__ g1w, const float* __restrict__ b1w,
    const float* __restrict__ g2w, const float* __restrict__ b2w)
{
    __shared__ short As[16 * 136];
    __shared__ short Ws[64 * 136];
    __shared__ short U1[16 * 136];
    __shared__ short U2[16 * 264];
    float* P = (float*)Ws;                 // 16*130*4 = 8320B <= 17408B

    const int tid  = threadIdx.x;
    const int lane = tid & 63;
    const int wv   = tid >> 6;
    const int col  = lane & 15;
    const int g    = lane >> 4;
    const int m0   = blockIdx.x * 16;
    const int cb   = wv * 16;

    bf16x8 wreg[4];
    auto loadPanel = [&](const short* base, int stride) {
        #pragma unroll
        for (int j = 0; j < 4; ++j) {
            const int i = tid + j * 256;
            wreg[j] = *(const bf16x8*)(base + (size_t)(i / 16) * stride + (i % 16) * 8);
        }
    };
    auto writePanel = [&]() {
        #pragma unroll
        for (int j = 0; j < 4; ++j) {
            const int i = tid + j * 256;
            *(bf16x8*)&Ws[(i / 16) * 136 + (i % 16) * 8] = wreg[j];
        }
    };

    {   // stage As (one bf16x8 per thread)
        const int r = tid / 16, c = (tid % 16) * 8;
        *(bf16x8*)&As[r * 136 + c] = *(const bf16x8*)(X + (size_t)(m0 + r) * 128 + c);
    }
    loadPanel(Wo, 128);                    // prologue: panel 0

    // ---- attn out-proj (rounds 0,1) ----
    f32x4 ya[2] = {};
    #pragma unroll
    for (int ch = 0; ch < 2; ++ch) {
        writePanel();
        if (ch == 0) loadPanel(Wo + (size_t)64 * 128, 128);
        else         loadPanel(W1, 128);
        asm volatile("s_waitcnt lgkmcnt(0)" ::: "memory");
        __builtin_amdgcn_s_barrier();
        #pragma unroll
        for (int k0 = 0; k0 < 128; k0 += 32) {
            bf16x8 a = *(bf16x8*)&As[col * 136 + k0 + g * 8];
            bf16x8 b = *(bf16x8*)&Ws[(cb + col) * 136 + k0 + g * 8];
            ya[ch] = __builtin_amdgcn_mfma_f32_16x16x32_bf16(a, b, ya[ch], 0, 0, 0);
        }
        __syncthreads();
    }

    #pragma unroll
    for (int ch = 0; ch < 2; ++ch) {
        const int cn = ch * 64 + cb + col;
        const float bb = bo[cn];
        #pragma unroll
        for (int r = 0; r < 4; ++r)
            P[(g * 4 + r) * 130 + cn] = ya[ch][r] + bb;
    }
    __syncthreads();

    // ---- LN1: residual from global hf; fp32 result to regs, bf16 to U1 ----
    float2 resid[4];
    #pragma unroll
    for (int rr = 0; rr < 4; ++rr) {
        const int row = wv * 4 + rr;
        const size_t t = m0 + row;
        float2 pv = *(float2*)&P[row * 130 + 2 * lane];
        float2 hv = ((const float2*)(hf + t * Hh))[lane];
        float a0 = hv.x + pv.x, a1 = hv.y + pv.y;
        float sum = a0 + a1;
        #pragma unroll
        for (int off = 32; off > 0; off >>= 1) sum += __shfl_xor(sum, off);
        const float mean = sum * (1.f / 128.f);
        const float d0 = a0 - mean, d1 = a1 - mean;
        float vs = d0 * d0 + d1 * d1;
        #pragma unroll
        for (int off = 32; off > 0; off >>= 1) vs += __shfl_xor(vs, off);
        const float rstd = rsqrtf(vs * (1.f / 128.f) + 1e-5f);
        float2 gv = ((const float2*)g1w)[lane];
        float2 bv = ((const float2*)b1w)[lane];
        float2 r = { d0 * rstd * gv.x + bv.x, d1 * rstd * gv.y + bv.y };
        resid[rr] = r;
        *(unsigned*)&U1[row * 136 + 2 * lane] = pack2_bf16(r.x, r.y);
    }
    __syncthreads();       // P reads + U1 writes done before Ws restage / U1 reads

    // ---- FFN stage 1 (rounds 2..5): U2 = relu(U1 @ W1^T + b1) ----
    #pragma unroll
    for (int ch = 0; ch < 4; ++ch) {
        writePanel();
        if (ch < 3) loadPanel(W1 + (size_t)(ch + 1) * 64 * 128, 128);
        else        loadPanel(W2, 256);
        asm volatile("s_waitcnt lgkmcnt(0)" ::: "memory");
        __builtin_amdgcn_s_barrier();
        f32x4 y1 = {};
        #pragma unroll
        for (int k0 = 0; k0 < 128; k0 += 32) {
            bf16x8 a = *(bf16x8*)&U1[col * 136 + k0 + g * 8];
            bf16x8 b = *(bf16x8*)&Ws[(cb + col) * 136 + k0 + g * 8];
            y1 = __builtin_amdgcn_mfma_f32_16x16x32_bf16(a, b, y1, 0, 0, 0);
        }
        __syncthreads();
        const int cn = ch * 64 + cb + col;
        const float bb = b1[cn];
        #pragma unroll
        for (int r = 0; r < 4; ++r)
            U2[(g * 4 + r) * 264 + cn] = f32_to_bf16_rne(fmaxf(y1[r] + bb, 0.f));
        // U2 ds_writes covered by the next round's lgkmcnt(0)+barrier
    }

    // ---- FFN stage 2 (rounds 6..9): yb = U2 @ W2^T ----
    f32x4 yb[2] = {};
    #pragma unroll
    for (int ch2 = 0; ch2 < 2; ++ch2) {
        #pragma unroll
        for (int kh = 0; kh < 2; ++kh) {
            writePanel();
            const int pidx = ch2 * 2 + kh;
            if (pidx < 3) {
                const int nj = pidx + 1;
                loadPanel(W2 + (size_t)(nj >> 1) * 64 * 256 + (nj & 1) * 128, 256);
            }
            asm volatile("s_waitcnt lgkmcnt(0)" ::: "memory");
            __builtin_amdgcn_s_barrier();
            #pragma unroll
            for (int k0 = 0; k0 < 128; k0 += 32) {
                bf16x8 a = *(bf16x8*)&U2[col * 264 + kh * 128 + k0 + g * 8];
                bf16x8 b = *(bf16x8*)&Ws[(cb + col) * 136 + k0 + g * 8];
                yb[ch2] = __builtin_amdgcn_mfma_f32_16x16x32_bf16(a, b, yb[ch2], 0, 0, 0);
            }
            __syncthreads();
        }
    }

    // ---- LN2 scatter + epilogue (residual from regs); write hf + hb ----
    #pragma unroll
    for (int ch2 = 0; ch2 < 2; ++ch2) {
        const int cn = ch2 * 64 + cb + col;
        const float bb = b2[cn];
        #pragma unroll
        for (int r = 0; r < 4; ++r)
            P[(g * 4 + r) * 130 + cn] = yb[ch2][r] + bb;
    }
    __syncthreads();

    #pragma unroll
    for (int rr = 0; rr < 4; ++rr) {
        const int row = wv * 4 + rr;
        const size_t t = m0 + row;
        float2 pv = *(float2*)&P[row * 130 + 2 * lane];
        float a0 = resid[rr].x + pv.x, a1 = resid[rr].y + pv.y;
        float sum = a0 + a1;
        #pragma unroll
        for (int off = 32; off > 0; off >>= 1) sum += __shfl_xor(sum, off);
        const float mean = sum * (1.f / 128.f);
        const float d0 = a0 - mean, d1 = a1 - mean;
        float vs = d0 * d0 + d1 * d1;
        #pragma unroll
        for (int off = 32; off > 0; off >>= 1) vs += __shfl_xor(vs, off);
        const float rstd = rsqrtf(vs * (1.f / 128.f) + 1e-5f);
        float2 gv = ((const float2*)g2w)[lane];
        float2 bv = ((const float2*)b2w)[lane];
        float2 r = { d0 * rstd * gv.x + bv.x, d1 * rstd * gv.y + bv.y };
        ((float2*)(hf + t * Hh))[lane] = r;
        *(unsigned*)&hb[t * Hh + lane * 2] = pack2_bf16(r.x, r.y);
    }
}

// ---------------------------------------------------------------------------
// Two-stage fused MLP — 16-row blocks (R12-verified), register-prefetch
// panel pipeline. Feature-fusion front-end (K=256, MID=128, DO_LN=0).
// ---------------------------------------------------------------------------
template<int K, int MID, bool DO_LN>
__global__ __launch_bounds__(256) void mlp2_kernel(
    const short* __restrict__ X,
    const short* __restrict__ W1, const float* __restrict__ b1,
    const short* __restrict__ W2, const float* __restrict__ b2,
    float* __restrict__ hf, short* __restrict__ hb,
    const float* __restrict__ gw, const float* __restrict__ bw)
{
    constexpr int STA = K + 8;
    constexpr int STU = MID + 8;
    constexpr int KP1  = K / 128;
    constexpr int KP2  = MID / 128;
    constexpr int NCH1 = MID / 64;
    constexpr int NP1  = NCH1 * KP1;
    constexpr int NP   = NP1 + 2 * KP2;
    __shared__ short As[16 * STA];
    __shared__ short Ws[64 * 136];
    __shared__ short U[16 * STU];
    float* P = (float*)Ws;                 // 8320B <= 17408B

    const int tid  = threadIdx.x;
    const int lane = tid & 63;
    const int wv   = tid >> 6;
    const int col  = lane & 15;
    const int g    = lane >> 4;
    const int m0   = blockIdx.x * 16;
    const int cb   = wv * 16;

    bf16x8 wreg[4];
    auto loadPanelIdx = [&](int idx) {
        const short* base;
        int stride;
        if (idx < NP1) {
            const int ch = idx / KP1, kh = idx % KP1;
            base = W1 + (size_t)(ch * 64) * K + kh * 128; stride = K;
        } else {
            const int jj = idx - NP1;
            const int ch2 = jj / KP2, kh = jj % KP2;
            base = W2 + (size_t)(ch2 * 64) * MID + kh * 128; stride = MID;
        }
        #pragma unroll
        for (int j = 0; j < 4; ++j) {
            const int i = tid + j * 256;
            wreg[j] = *(const bf16x8*)(base + (size_t)(i / 16) * stride + (i % 16) * 8);
        }
    };
    auto writePanel = [&]() {
        #pragma unroll
        for (int j = 0; j < 4; ++j) {
            const int i = tid + j * 256;
            *(bf16x8*)&Ws[(i / 16) * 136 + (i % 16) * 8] = wreg[j];
        }
    };

    for (int i = tid; i < 16 * (K / 8); i += 256) {
        const int r = i / (K / 8), c = (i % (K / 8)) * 8;
        *(bf16x8*)&As[r * STA + c] = *(const bf16x8*)(X + (size_t)(m0 + r) * K + c);
    }
    loadPanelIdx(0);
    int pidx = 0;

    // ---- stage 1: u = relu(X@W1^T + b1), u in LDS ----
    #pragma unroll
    for (int ch = 0; ch < NCH1; ++ch) {
        f32x4 ya = {};
        #pragma unroll
        for (int kh = 0; kh < KP1; ++kh) {
            writePanel();
            ++pidx;
            if (pidx < NP) loadPanelIdx(pidx);
            asm volatile("s_waitcnt lgkmcnt(0)" ::: "memory");
            __builtin_amdgcn_s_barrier();
            #pragma unroll
            for (int k0 = 0; k0 < 128; k0 += 32) {
                bf16x8 a = *(bf16x8*)&As[col * STA + kh * 128 + k0 + g * 8];
                bf16x8 b = *(bf16x8*)&Ws[(cb + col) * 136 + k0 + g * 8];
                ya = __builtin_amdgcn_mfma_f32_16x16x32_bf16(a, b, ya, 0, 0, 0);
            }
            __syncthreads();
        }
        const int cn = ch * 64 + cb + col;
        const float bb = b1[cn];
        #pragma unroll
        for (int r = 0; r < 4; ++r)
            U[(g * 4 + r) * STU + cn] = f32_to_bf16_rne(fmaxf(ya[r] + bb, 0.f));
    }

    // ---- stage 2: y = u@W2^T + b2 ----
    f32x4 yb[2] = {};
    #pragma unroll
    for (int ch2 = 0; ch2 < 2; ++ch2) {
        #pragma unroll
        for (int kh = 0; kh < KP2; ++kh) {
            writePanel();
            ++pidx;
            if (pidx < NP) loadPanelIdx(pidx);
            asm volatile("s_waitcnt lgkmcnt(0)" ::: "memory");
            __builtin_amdgcn_s_barrier();
            #pragma unroll
            for (int k0 = 0; k0 < 128; k0 += 32) {
                bf16x8 a = *(bf16x8*)&U[col * STU + kh * 128 + k0 + g * 8];
                bf16x8 b = *(bf16x8*)&Ws[(cb + col) * 136 + k0 + g * 8];
                yb[ch2] = __builtin_amdgcn_mfma_f32_16x16x32_bf16(a, b, yb[ch2], 0, 0, 0);
            }
            __syncthreads();
        }
    }

    // ---- P scatter (aliases Ws) + epilogue ----
    #pragma unroll
    for (int ch2 = 0; ch2 < 2; ++ch2) {
        const int cn = ch2 * 64 + cb + col;
        const float bb = b2[cn];
        #pragma unroll
        for (int r = 0; r < 4; ++r)
            P[(g * 4 + r) * 130 + cn] = yb[ch2][r] + bb;
    }
    __syncthreads();

    #pragma unroll
    for (int rr = 0; rr < 4; ++rr) {
        const int row = wv * 4 + rr;
        const size_t t = m0 + row;
        float2 pv = *(float2*)&P[row * 130 + 2 * lane];
        if (DO_LN) {
            float2 hv = ((const float2*)(hf + t * Hh))[lane];
            float a0 = hv.x + pv.x, a1 = hv.y + pv.y;
            float sum = a0 + a1;
            #pragma unroll
            for (int off = 32; off > 0; off >>= 1) sum += __shfl_xor(sum, off);
            const float mean = sum * (1.f / 128.f);
            const float d0 = a0 - mean, d1 = a1 - mean;
            float vs = d0 * d0 + d1 * d1;
            #pragma unroll
            for (int off = 32; off > 0; off >>= 1) vs += __shfl_xor(vs, off);
            const float rstd = rsqrtf(vs * (1.f / 128.f) + 1e-5f);
            float2 gv = ((const float2*)gw)[lane];
            float2 bv = ((const float2*)bw)[lane];
            float2 r = { d0 * rstd * gv.x + bv.x, d1 * rstd * gv.y + bv.y };
            ((float2*)(hf + t * Hh))[lane] = r;
            *(unsigned*)&hb[t * Hh + lane * 2] = pack2_bf16(r.x, r.y);
        } else {
            ((float2*)(hf + t * Hh))[lane] = pv;
            *(unsigned*)&hb[t * Hh + lane * 2] = pack2_bf16(pv.x, pv.y);
        }
    }
}

// ---------------------------------------------------------------------------
// Fused head (R12-verified) + register-prefetch panel pipeline
// (3 panels: W1b rows 0-63, W1b rows 64-127, DW1b rows 0-63; stride 128).
// R13 note: folding this into postattn regressed — keep as own dispatch.
// ---------------------------------------------------------------------------
__global__ __launch_bounds__(256) void head_kernel(
    const short* __restrict__ X,
    const short* __restrict__ W1b, const float* __restrict__ b1,
    const short* __restrict__ DW1b, const float* __restrict__ db1,
    const float* __restrict__ w2, const float* __restrict__ b2,
    const float* __restrict__ dw2, const float* __restrict__ db2,
    float* __restrict__ out)
{
    constexpr int K = 128, ST = K + 8;
    __shared__ short As[32 * ST];
    __shared__ short Ws[64 * ST];
    __shared__ float P[32 * 196];

    const int tid  = threadIdx.x;
    const int lane = tid & 63;
    const int wv   = tid >> 6;
    const int col  = lane & 15;
    const int g    = lane >> 4;
    const int m0   = blockIdx.x * 32;
    const int mst  = (wv & 1) * 16;
    const int cb   = (wv >> 1) * 32;

    bf16x8 wreg[4];
    auto loadPanel = [&](const short* base) {
        #pragma unroll
        for (int j = 0; j < 4; ++j) {
            const int i = tid + j * 256;
            wreg[j] = *(const bf16x8*)(base + (size_t)(i / 16) * K + (i % 16) * 8);
        }
    };
    auto writePanel = [&]() {
        #pragma unroll
        for (int j = 0; j < 4; ++j) {
            const int i = tid + j * 256;
            *(bf16x8*)&Ws[(i / 16) * ST + (i % 16) * 8] = wreg[j];
        }
    };

    for (int i = tid; i < 32 * (K / 8); i += 256) {
        const int r = i / (K / 8), c = (i % (K / 8)) * 8;
        *(bf16x8*)&As[r * ST + c] = *(const bf16x8*)(X + (size_t)(m0 + r) * K + c);
    }
    loadPanel(W1b);

    f32x4 ya[3][2] = {};
    #pragma unroll
    for (int ch = 0; ch < 3; ++ch) {
        writePanel();
        if (ch == 0) loadPanel(W1b + (size_t)64 * K);
        else if (ch == 1) loadPanel(DW1b);
        asm volatile("s_waitcnt lgkmcnt(0)" ::: "memory");
        __builtin_amdgcn_s_barrier();
        __builtin_amdgcn_sched_barrier(0);
        #pragma unroll
        for (int k0 = 0; k0 < K; k0 += 32) {
            bf16x8 a = *(bf16x8*)&As[(mst + col) * ST + k0 + g * 8];
            #pragma unroll
            for (int f = 0; f < 2; ++f) {
                bf16x8 b = *(bf16x8*)&Ws[(cb + f * 16 + col) * ST + k0 + g * 8];
                ya[ch][f] = __builtin_amdgcn_mfma_f32_16x16x32_bf16(a, b, ya[ch][f], 0, 0, 0);
            }
        }
        __syncthreads();
    }

    #pragma unroll
    for (int ch = 0; ch < 3; ++ch)
        #pragma unroll
        for (int f = 0; f < 2; ++f) {
            const int cn = ch * 64 + cb + f * 16 + col;
            const float bb = (cn < 128) ? b1[cn] : db1[cn - 128];
            #pragma unroll
            for (int r = 0; r < 4; ++r)
                P[(mst + g * 4 + r) * 196 + cn] = fmaxf(ya[ch][f][r] + bb, 0.f);
        }
    __syncthreads();

    const float w20 = w2[2 * lane],       w21 = w2[2 * lane + 1];
    const float w22 = w2[128 + 2 * lane], w23 = w2[129 + 2 * lane];
    const float w24 = w2[256 + 2 * lane], w25 = w2[257 + 2 * lane];
    const float dwl = dw2[lane];
    float qacc = 0.f;
    #pragma unroll
    for (int rr = 0; rr < 8; ++rr) {
        const int row = wv * 8 + rr;
        const size_t t = m0 + row;
        const float x0 = P[row * 196 + 2 * lane];
        const float x1 = P[row * 196 + 2 * lane + 1];
        float s0 = x0 * w20 + x1 * w21;
        float s1 = x0 * w22 + x1 * w23;
        float s2 = x0 * w24 + x1 * w25;
        float d  = P[row * 196 + 128 + lane] * dwl;
        #pragma unroll
        for (int off = 32; off > 0; off >>= 1) {
            s0 += __shfl_xor(s0, off);
            s1 += __shfl_xor(s1, off);
            s2 += __shfl_xor(s2, off);
            d  += __shfl_xor(d,  off);
        }
        if (lane == 0) {
            out[t * 3 + 0] = s0 + b2[0];
            out[t * 3 + 1] = s1 + b2[1];
            out[t * 3 + 2] = s2 + b2[2];
            const float prob = 1.f / (1.f + __expf(-(d + db2[0])));
            out[24576 + t] = prob;
            qacc += prob;
        }
    }
    if (lane == 0)
        atomicAdd(&out[32768 + (m0 >> 11)], qacc * (1.f / (float)Nn));
}

// ---------------------------------------------------------------------------
// MFMA flash attention — R12-green kernel, unchanged (no-max softmax,
// ones-MFMA row sum, reg-prefetch pipeline, raw lgkm-only barrier,
// setprio around the MFMA+exp2 cluster). The __syncthreads at tile top is
// LOAD-BEARING (phase separation, R11 post-mortem).
// ---------------------------------------------------------------------------
constexpr int KT = 128;
constexpr int KS = 28;
constexpr int VS = 132;

__global__ __launch_bounds__(256) void attn_kernel(
    const short* __restrict__ qkv, short* __restrict__ out)
{
    __shared__ short Ks[KT * KS];
    __shared__ short Vs[DHh * VS];

    const int tid  = threadIdx.x;
    const int lane = tid & 63;
    const int wv   = tid >> 6;
    const int col  = lane & 15;
    const int g    = lane >> 4;
    const int hd   = blockIdx.y;
    const int b    = blockIdx.z;
    const int q0   = blockIdx.x * 64 + wv * 16;

    const short* base = qkv + (size_t)b * Nn * 384;

    bf16x8 qf = {};
    if (g < 2) {
        bf16x8 qraw = *(const bf16x8*)(base + (size_t)(q0 + col) * 384 + hd * DHh + g * 8);
        const float qs = 0.25f * LOG2E;
        #pragma unroll
        for (int i = 0; i < 8; ++i)
            qf[i] = f32_to_bf16_rne(bf16_to_f32(qraw[i]) * qs);
    }

    f32x4 o    = {0.f, 0.f, 0.f, 0.f};
    f32x4 lacc = {0.f, 0.f, 0.f, 0.f};
    const short one_bf16 = (short)0x3F80;
    const bf16x8 ones = { one_bf16, one_bf16, one_bf16, one_bf16,
                          one_bf16, one_bf16, one_bf16, one_bf16 };

    const int ksr = tid >> 1;
    const int ksd = (tid & 1) * 8;
    const int va  = tid >> 2;
    const int vd  = (tid & 3) * 4;

    const short* kptr = base + (size_t)ksr * 384 + Hh + hd * DHh + ksd;
    const short* vptr = base + (size_t)(2 * va) * 384 + 2 * Hh + hd * DHh + vd;
    bf16x8 kreg = *(const bf16x8*)kptr;
    bf16x4 vr0  = *(const bf16x4*)vptr;
    bf16x4 vr1  = *(const bf16x4*)(vptr + 384);

    for (int kt = 0; kt < Nn; kt += KT) {
        __syncthreads();

        *(bf16x8*)&Ks[ksr * KS + ksd] = kreg;
        {
            unsigned a0 = ((const unsigned*)&vr0)[0], a1 = ((const unsigned*)&vr0)[1];
            unsigned b0 = ((const unsigned*)&vr1)[0], b1 = ((const unsigned*)&vr1)[1];
            *(unsigned*)&Vs[(vd + 0) * VS + 2 * va] = __builtin_amdgcn_perm(b0, a0, 0x05040100);
            *(unsigned*)&Vs[(vd + 1) * VS + 2 * va] = __builtin_amdgcn_perm(b0, a0, 0x07060302);
            *(unsigned*)&Vs[(vd + 2) * VS + 2 * va] = __builtin_amdgcn_perm(b1, a1, 0x05040100);
            *(unsigned*)&Vs[(vd + 3) * VS + 2 * va] = __builtin_amdgcn_perm(b1, a1, 0x07060302);
        }

        if (kt + KT < Nn) {
            kptr += KT * 384;
            vptr += KT * 384;
            kreg = *(const bf16x8*)kptr;
            vr0  = *(const bf16x4*)vptr;
            vr1  = *(const bf16x4*)(vptr + 384);
        }

        asm volatile("s_waitcnt lgkmcnt(0)" ::: "memory");
        __builtin_amdgcn_s_barrier();

        __builtin_amdgcn_s_setprio(1);
        #pragma unroll
        for (int s = 0; s < 4; ++s) {
            bf16x8 kf0 = {}, kf1 = {};
            if (g < 2) {
                kf0 = *(bf16x8*)&Ks[(s * 32 + col) * KS + g * 8];
                kf1 = *(bf16x8*)&Ks[(s * 32 + 16 + col) * KS + g * 8];
            }
            f32x4 z = {0.f, 0.f, 0.f, 0.f};
            f32x4 sA = __builtin_amdgcn_mfma_f32_16x16x32_bf16(kf0, qf, z, 0, 0, 0);
            f32x4 sB = __builtin_amdgcn_mfma_f32_16x16x32_bf16(kf1, qf, z, 0, 0, 0);

            union { bf16x8 v; unsigned u[4]; } pf;
            pf.u[0] = pack2_bf16(__builtin_amdgcn_exp2f(sA[0]),
                                 __builtin_amdgcn_exp2f(sA[1]));
            pf.u[1] = pack2_bf16(__builtin_amdgcn_exp2f(sA[2]),
                                 __builtin_amdgcn_exp2f(sA[3]));
            pf.u[2] = pack2_bf16(__builtin_amdgcn_exp2f(sB[0]),
                                 __builtin_amdgcn_exp2f(sB[1]));
            pf.u[3] = pack2_bf16(__builtin_amdgcn_exp2f(sB[2]),
                                 __builtin_amdgcn_exp2f(sB[3]));

            bf16x8 vf;
            ((bf16x4*)&vf)[0] = *(bf16x4*)&Vs[col * VS + s * 32 + g * 4];
            ((bf16x4*)&vf)[1] = *(bf16x4*)&Vs[col * VS + s * 32 + 16 + g * 4];

            o    = __builtin_amdgcn_mfma_f32_16x16x32_bf16(pf.v, vf,   o,    0, 0, 0);
            lacc = __builtin_amdgcn_mfma_f32_16x16x32_bf16(pf.v, ones, lacc, 0, 0, 0);
        }
        __builtin_amdgcn_s_setprio(0);
    }

    #pragma unroll
    for (int r = 0; r < 4; ++r) {
        const float inv = __builtin_amdgcn_rcpf(lacc[r]);
        out[(size_t)(b * Nn + q0 + g * 4 + r) * Hh + hd * DHh + col] =
            f32_to_bf16_rne(o[r] * inv);
    }
}

// ---------------------------------------------------------------------------
extern "C" void kernel_launch(void* const* d_in, const int* in_sizes, int n_in,
                              void* d_out, int out_size, void* d_ws, size_t ws_size,
                              hipStream_t stream)
{
    char* W8 = (char*)d_ws;
    float* hf   = (float*)(W8 + 0);            // 4MB  fp32 residual spine
    short* hb   = (short*)(W8 + 4194304);      // 2MB  bf16 mirror
    short* wb   = (short*)(W8 + 6291456);      // 1MB  bf16 weights
    char*  regA = W8 + 7340032;                // 6MB  xb / qkvb
    char*  regB = W8 + 13631488;               // 2MB  attno

    short* xb    = (short*)regA;               // [8192,256]
    short* qkvb  = (short*)regA;               // [8192,384]
    short* attno = (short*)regB;               // [8192,128]
    float* out   = (float*)d_out;

    const int wsz[12]  = {32768,16384,49152,16384,32768,32768,49152,16384,32768,32768,16384,8192};
    const int wsrc[12] = {1, 3, 5, 7, 9, 11, 17, 19, 21, 23, 29, 33};
    int woff[13]; woff[0] = 0;
    for (int i = 0; i < 12; ++i) woff[i + 1] = woff[i] + wsz[i];

    CvtJobs jobs;
    int acc = 0;
    for (int i = 0; i < 12; ++i) {
        jobs.src[i] = (const float*)d_in[wsrc[i]];
        jobs.dst[i] = wb + woff[i];
        jobs.off[i] = acc;
        acc += wsz[i] / 4;
    }
    jobs.src[12] = (const float*)d_in[0];
    jobs.dst[12] = xb;
    jobs.off[12] = acc;
    acc += (MTOK * Cc) / 4;
    jobs.off[13] = acc;
    jobs.qzero = out + 32768;

    hipLaunchKernelGGL(cvt_kernel, dim3((acc + 255) / 256), dim3(256), 0, stream, jobs);

    // feature fusion: h = relu(x@fw1^T+b1)@fw2^T+b2  (one fused dispatch)
    hipLaunchKernelGGL((mlp2_kernel<256, 128, false>), dim3(MTOK / 16), dim3(256), 0,
                       stream, xb, wb + woff[0], (const float*)d_in[2],
                       wb + woff[1], (const float*)d_in[4], hf, hb, nullptr, nullptr);

    for (int l = 0; l < 2; ++l) {
        const int ib = 5 + l * 12;
        const int wbase = 2 + l * 4;
        hipLaunchKernelGGL(qkv_gemm_kernel, dim3(384 / 64, MTOK / 64), dim3(256), 0, stream,
                           hb, wb + woff[wbase + 0], (const float*)d_in[ib + 1], qkvb);
        hipLaunchKernelGGL(attn_kernel, dim3(Nn / 64, NHh, Bb), dim3(256), 0, stream,
                           qkvb, attno);
        // fused out-proj + LN1 + FFN + LN2 (one dispatch per layer)
        hipLaunchKernelGGL(postattn_kernel, dim3(MTOK / 16), dim3(256), 0, stream,
                           attno, wb + woff[wbase + 1], (const float*)d_in[ib + 3],
                           wb + woff[wbase + 2], (const float*)d_in[ib + 5],
                           wb + woff[wbase + 3], (const float*)d_in[ib + 7],
                           hf, hb,
                           (const float*)d_in[ib + 8], (const float*)d_in[ib + 9],
                           (const float*)d_in[ib + 10], (const float*)d_in[ib + 11]);
    }

    hipLaunchKernelGGL(head_kernel, dim3(MTOK / 32), dim3(256), 0, stream,
                       hb, wb + woff[10], (const float*)d_in[30],
                       wb + woff[11], (const float*)d_in[34],
                       (const float*)d_in[31], (const float*)d_in[32],
                       (const float*)d_in[35], (const float*)d_in[36], out);
}